// Round 15
// baseline (5114.141 us; speedup 1.0000x reference)
//
#include <hip/hip_runtime.h>
#include <math.h>

#define VOCABN 32000
#define HIDN 512
#define BN 64
#define TSTEPS 33   // MAX_LEN + 1
#define OUTROWS (TSTEPS * VOCABN)
#define NVBLK 500   // logits grid; each block = 4 waves = 4 16-row v-tiles
#define NVT 2000    // total 16-row v-tiles
#define GSLICE 8    // gates K-slices

typedef float f4 __attribute__((ext_vector_type(4)));
typedef __bf16 bf16x8 __attribute__((ext_vector_type(8)));
typedef unsigned short u16x8 __attribute__((ext_vector_type(8)));

__device__ __forceinline__ unsigned short f2bf_rn(float f) {
    unsigned int u = __builtin_bit_cast(unsigned int, f);
    u += 0x7FFFu + ((u >> 16) & 1u);
    return (unsigned short)(u >> 16);
}
__device__ __forceinline__ float bfbits2f(unsigned short s) {
    unsigned int u = ((unsigned int)s) << 16;
    return __builtin_bit_cast(float, u);
}
__device__ __forceinline__ float sigf(float x) { return 1.f / (1.f + expf(-x)); }
__device__ __forceinline__ void olmerge(float& m, float& s, int& idx,
                                        float mo, float so, int io) {
    float M = fmaxf(m, mo);
    s = s * __expf(m - M) + so * __expf(mo - M);
    idx = (mo > m) ? io : ((mo == m) ? (io < idx ? io : idx) : idx);
    m = M;
}

// ---------------- init ----------------
__global__ __launch_bounds__(256) void k_init(const float* __restrict__ eh,
                                              const float* __restrict__ ec,
                                              float* __restrict__ h,
                                              float* __restrict__ c,
                                              int* __restrict__ tok,
                                              int* __restrict__ counters) {
    int i = blockIdx.x * 256 + threadIdx.x;
    if (i < BN * HIDN) { h[i] = eh[i]; c[i] = ec[i]; }
    if (i < BN) tok[i] = 1; // SOS
    if (i < TSTEPS) counters[i] = 0;
}

// ---------------- one-time: pack fc_w into pre-swizzled bf16 hi/lo A-fragments ----
// layout: whiP[((vt*16 + kc)*64 + lane)*8 + j] = hi(fc_w[vt*16 + (lane&15)][kc*32 + (lane>>4)*8 + j])
__global__ __launch_bounds__(256) void k_conv(const float* __restrict__ fc_w,
                                              unsigned short* __restrict__ whiP,
                                              unsigned short* __restrict__ wloP) {
    const int vt = blockIdx.x;  // 0..1999
    const int tid = threadIdx.x;
    #pragma unroll
    for (int i = 0; i < 4; ++i) {
        const int s = tid + 256 * i;            // 0..1023
        const int kc = s >> 6, lane = s & 63;
        const int v = vt * 16 + (lane & 15);
        const int k = kc * 32 + (lane >> 4) * 8;
        const float* src = fc_w + (size_t)v * 512 + k;
        f4 a = *(const f4*)src;
        f4 b = *(const f4*)(src + 4);
        u16x8 hi, lo;
        #pragma unroll
        for (int e = 0; e < 4; ++e) {
            unsigned short ha = f2bf_rn(a[e]);
            hi[e] = ha; lo[e] = f2bf_rn(a[e] - bfbits2f(ha));
            unsigned short hb = f2bf_rn(b[e]);
            hi[4 + e] = hb; lo[4 + e] = f2bf_rn(b[e] - bfbits2f(hb));
        }
        const size_t o = ((size_t)(vt * 16 + kc) * 64 + lane) * 8;
        *(u16x8*)&whiP[o] = hi;
        *(u16x8*)&wloP[o] = lo;
    }
}

// ---------------- K1a: partial gates GEMM (fp32), 8 K-slices ----------------
// grid = 256 blocks: j0 = (bid&31)*64, ks = bid>>5 (k0 = ks*128)
__global__ __launch_bounds__(256) void k_gates(const float* __restrict__ W_ih,
                                               const float* __restrict__ W_hh,
                                               const float* __restrict__ emb,
                                               const float* __restrict__ h,
                                               const int* __restrict__ tok,
                                               float* __restrict__ part) {
    __shared__ float w_s[64][68];
    __shared__ float x_s[64][68];
    const int tid = threadIdx.x;
    const int j0 = (blockIdx.x & 31) * 64;
    const int ks = blockIdx.x >> 5;          // 0..7
    const int k0 = ks * 128;
    const int tx = tid & 15;
    const int ty = tid >> 4;
    const int r  = tid >> 2;
    const int cq = (tid & 3) * 16;

    float acc[4][4];
    #pragma unroll
    for (int i = 0; i < 4; ++i)
        #pragma unroll
        for (int j = 0; j < 4; ++j) acc[i][j] = 0.f;

    for (int kk = 0; kk < 128; kk += 64) {
        const int k = k0 + kk;               // never straddles the 512 boundary
        __syncthreads();
        {
            const float* src = (k < 512) ? (W_ih + (size_t)(j0 + r) * 512 + k + cq)
                                         : (W_hh + (size_t)(j0 + r) * 512 + (k - 512) + cq);
            const f4* s4 = (const f4*)src;
            f4* d4 = (f4*)&w_s[r][cq];
            d4[0] = s4[0]; d4[1] = s4[1]; d4[2] = s4[2]; d4[3] = s4[3];
        }
        {
            const float* src = (k < 512) ? (emb + (size_t)tok[r] * 512 + k + cq)
                                         : (h + (size_t)r * 512 + (k - 512) + cq);
            const f4* s4 = (const f4*)src;
            f4* d4 = (f4*)&x_s[r][cq];
            d4[0] = s4[0]; d4[1] = s4[1]; d4[2] = s4[2]; d4[3] = s4[3];
        }
        __syncthreads();
        #pragma unroll 4
        for (int c4 = 0; c4 < 64; c4 += 4) {
            f4 wv[4], xv[4];
            #pragma unroll
            for (int jj = 0; jj < 4; ++jj) wv[jj] = *(const f4*)&w_s[16 * jj + tx][c4];
            #pragma unroll
            for (int bb = 0; bb < 4; ++bb) xv[bb] = *(const f4*)&x_s[16 * bb + ty][c4];
            #pragma unroll
            for (int e = 0; e < 4; ++e)
                #pragma unroll
                for (int bb = 0; bb < 4; ++bb)
                    #pragma unroll
                    for (int jj = 0; jj < 4; ++jj)
                        acc[bb][jj] += xv[bb][e] * wv[jj][e];
        }
    }
    #pragma unroll
    for (int bb = 0; bb < 4; ++bb) {
        const int b = 16 * bb + ty;
        #pragma unroll
        for (int jj = 0; jj < 4; ++jj)
            part[((size_t)(ks * 64 + b)) * 2048 + j0 + 16 * jj + tx] = acc[bb][jj];
    }
}

// ---------------- K1b: reduce 8 partials + LSTM cell; writes h + bf16 hi/lo ------
__global__ __launch_bounds__(256) void k_cell(const float* __restrict__ part,
                                              const float* __restrict__ b_ih,
                                              const float* __restrict__ b_hh,
                                              float* __restrict__ h,
                                              float* __restrict__ c,
                                              unsigned short* __restrict__ hhi,
                                              unsigned short* __restrict__ hlo) {
    const int e = blockIdx.x * 256 + threadIdx.x; // b*512+u
    const int b = e >> 9, u = e & 511;
    float g[4];
    #pragma unroll
    for (int gi = 0; gi < 4; ++gi) {
        const int j = gi * 512 + u;
        float s = b_ih[j] + b_hh[j];
        #pragma unroll
        for (int ks = 0; ks < GSLICE; ++ks) s += part[((size_t)(ks * 64 + b)) * 2048 + j];
        g[gi] = s;
    }
    const float ig = sigf(g[0]);
    const float fg = sigf(g[1]);
    const float gg = tanhf(g[2]);
    const float og = sigf(g[3]);
    const float cn = fg * c[e] + ig * gg;
    const float hn = og * tanhf(cn);
    c[e] = cn;
    h[e] = hn;
    const unsigned short hi = f2bf_rn(hn);
    hhi[e] = hi;
    hlo[e] = f2bf_rn(hn - bfbits2f(hi));
}

// ---------------- K2: logits GEMM (round-10 body) + in-kernel last-block combine ---
// grid 500 x 256. Wave w handles v-tile vt = bid*4+w (16 rows), all 64 b.
// After the per-block partial write, a device-scope counter identifies the last
// block, which performs the wide 500-way combine -> tok[b], Lb[t][b].
__global__ __launch_bounds__(256) void k_logits(const unsigned short* __restrict__ whiP,
                                                const unsigned short* __restrict__ wloP,
                                                const float* __restrict__ fc_b,
                                                const unsigned short* __restrict__ hhi,
                                                const unsigned short* __restrict__ hlo,
                                                float* __restrict__ outrow,
                                                float* __restrict__ pm,
                                                float* __restrict__ ps,
                                                int* __restrict__ pi,
                                                int* __restrict__ tok,
                                                float* __restrict__ Lb,
                                                int* __restrict__ counter,
                                                int t) {
    __shared__ float red_m[4 * 64];
    __shared__ float red_s[4 * 64];
    __shared__ int   red_i[4 * 64];
    __shared__ float cm[256], cs[256];
    __shared__ int   ci[256];
    __shared__ int   isLast;

    const int tid  = threadIdx.x;
    const int w    = tid >> 6;
    const int lane = tid & 63;
    const int li   = lane & 15;
    const int lg   = lane >> 4;
    const int vt   = blockIdx.x * 4 + w;

    f4 acc[4];
    #pragma unroll
    for (int bf = 0; bf < 4; ++bf) acc[bf] = (f4){0.f, 0.f, 0.f, 0.f};

    const unsigned short* Ah = whiP + (size_t)vt * 8192 + lane * 8;
    const unsigned short* Al = wloP + (size_t)vt * 8192 + lane * 8;
    int boff[4];
    #pragma unroll
    for (int bf = 0; bf < 4; ++bf) boff[bf] = (li + 16 * bf) * 512 + lg * 8;

    #pragma unroll 4
    for (int kc = 0; kc < 16; ++kc) {
        bf16x8 Avh = *(const bf16x8*)(Ah + kc * 512);
        bf16x8 Avl = *(const bf16x8*)(Al + kc * 512);
        #pragma unroll
        for (int bf = 0; bf < 4; ++bf) {
            bf16x8 Bh = *(const bf16x8*)&hhi[boff[bf] + kc * 32];
            bf16x8 Bl = *(const bf16x8*)&hlo[boff[bf] + kc * 32];
            acc[bf] = __builtin_amdgcn_mfma_f32_16x16x32_bf16(Avh, Bh, acc[bf], 0, 0, 0);
            acc[bf] = __builtin_amdgcn_mfma_f32_16x16x32_bf16(Avl, Bh, acc[bf], 0, 0, 0);
            acc[bf] = __builtin_amdgcn_mfma_f32_16x16x32_bf16(Avh, Bl, acc[bf], 0, 0, 0);
        }
    }

    // ---- epilogue: bias, store raw logits, per-b online (max, argmax, sumexp) ----
    const int vbase = vt * 16;
    const f4 bias = *(const f4*)&fc_b[vbase + lg * 4];

    #pragma unroll
    for (int bf = 0; bf < 4; ++bf) {
        f4 x = acc[bf] + bias;
        acc[bf] = x;
        const int b = li + 16 * bf;
        *(f4*)&outrow[(size_t)b * OUTROWS + vbase + lg * 4] = x;
    }

    #pragma unroll
    for (int bf = 0; bf < 4; ++bf) {
        float m = -1e30f; int idx = 0;
        #pragma unroll
        for (int rg = 0; rg < 4; ++rg) {
            float x = acc[bf][rg];
            if (x > m) { m = x; idx = vbase + lg * 4 + rg; }
        }
        float s = 0.f;
        #pragma unroll
        for (int rg = 0; rg < 4; ++rg) s += __expf(acc[bf][rg] - m);
        #pragma unroll
        for (int off = 16; off <= 32; off <<= 1) {
            float mo = __shfl_xor(m, off);
            float so = __shfl_xor(s, off);
            int   io = __shfl_xor(idx, off);
            olmerge(m, s, idx, mo, so, io);
        }
        if (lg == 0) {
            red_m[w * 64 + li + 16 * bf] = m;
            red_s[w * 64 + li + 16 * bf] = s;
            red_i[w * 64 + li + 16 * bf] = idx;
        }
    }
    __syncthreads();
    if (tid < 64) {
        float m = red_m[tid]; float s = red_s[tid]; int idx = red_i[tid];
        #pragma unroll
        for (int w2 = 1; w2 < 4; ++w2)
            olmerge(m, s, idx, red_m[w2 * 64 + tid], red_s[w2 * 64 + tid], red_i[w2 * 64 + tid]);
        pm[blockIdx.x * 64 + tid] = m;
        ps[blockIdx.x * 64 + tid] = s;
        pi[blockIdx.x * 64 + tid] = idx;
    }

    // ---- last-block combine: device-scope release -> acquire, then wide scan ----
    __threadfence();   // make this block's pm/ps/pi (and out) visible device-wide
    if (tid == 0) {
        int done = __hip_atomic_fetch_add(counter, 1, __ATOMIC_ACQ_REL,
                                          __HIP_MEMORY_SCOPE_AGENT);
        isLast = (done == NVBLK - 1) ? 1 : 0;
    }
    __syncthreads();
    if (isLast) {
        const int b = tid & 63;
        const int q = tid >> 6;              // 0..3, each scans 125 blocks
        float m = -1e30f, s = 0.f; int idx = 0;
        #pragma unroll 8
        for (int blk = q * 125; blk < q * 125 + 125; ++blk)
            olmerge(m, s, idx, pm[blk * 64 + b], ps[blk * 64 + b], pi[blk * 64 + b]);
        cm[tid] = m; cs[tid] = s; ci[tid] = idx;
        __syncthreads();
        if (tid < 64) {
            float m0 = cm[tid], s0 = cs[tid]; int i0 = ci[tid];
            #pragma unroll
            for (int q2 = 1; q2 < 4; ++q2)
                olmerge(m0, s0, i0, cm[q2 * 64 + tid], cs[q2 * 64 + tid], ci[q2 * 64 + tid]);
            tok[tid] = i0;
            Lb[t * 64 + tid] = m0 + logf(s0);
        }
    }
}

// ---------------- final: out[b][t][v] -= L[t][b] ----------------
__global__ __launch_bounds__(256) void k_sub(float* __restrict__ out,
                                             const float* __restrict__ Lb) {
    const int N4 = BN * OUTROWS / 4;
    for (int i4 = blockIdx.x * 256 + threadIdx.x; i4 < N4; i4 += gridDim.x * 256) {
        const int i = i4 * 4;
        const int b = i / OUTROWS;
        const int rem = i - b * OUTROWS;
        const int t = rem / VOCABN;
        f4 x = *(const f4*)&out[i];
        const float L = Lb[t * 64 + b];
        x[0] -= L; x[1] -= L; x[2] -= L; x[3] -= L;
        *(f4*)&out[i] = x;
    }
}

// ---------------- final: decoder_hidden = h ----------------
__global__ __launch_bounds__(256) void k_copyh(const float* __restrict__ h,
                                               float* __restrict__ dst) {
    int i = blockIdx.x * 256 + threadIdx.x;
    if (i < BN * HIDN) dst[i] = h[i];
}

// =================== fallback (small ws): fp32 logits + softmax ===========
__global__ __launch_bounds__(256) void k_logits_f32(const float* __restrict__ fc_w,
                                                    const float* __restrict__ fc_b,
                                                    const float* __restrict__ h,
                                                    float* __restrict__ outrow) {
    __shared__ float w_s[64][68];
    __shared__ float h_s[64][68];
    const int tid = threadIdx.x;
    const int v0 = blockIdx.x * 64;
    const int tx = tid & 15;
    const int ty = tid >> 4;
    const int r  = tid >> 2;
    const int cq = (tid & 3) * 16;

    float acc[4][4];
    #pragma unroll
    for (int i = 0; i < 4; ++i)
        #pragma unroll
        for (int j = 0; j < 4; ++j) acc[i][j] = 0.f;

    for (int k = 0; k < 512; k += 64) {
        __syncthreads();
        {
            const f4* s4 = (const f4*)(fc_w + (size_t)(v0 + r) * 512 + k + cq);
            f4* d4 = (f4*)&w_s[r][cq];
            d4[0] = s4[0]; d4[1] = s4[1]; d4[2] = s4[2]; d4[3] = s4[3];
        }
        {
            const f4* s4 = (const f4*)(h + (size_t)r * 512 + k + cq);
            f4* d4 = (f4*)&h_s[r][cq];
            d4[0] = s4[0]; d4[1] = s4[1]; d4[2] = s4[2]; d4[3] = s4[3];
        }
        __syncthreads();
        #pragma unroll 4
        for (int c4 = 0; c4 < 64; c4 += 4) {
            f4 wv[4], hv[4];
            #pragma unroll
            for (int vv = 0; vv < 4; ++vv) wv[vv] = *(const f4*)&w_s[16 * vv + tx][c4];
            #pragma unroll
            for (int bb = 0; bb < 4; ++bb) hv[bb] = *(const f4*)&h_s[16 * bb + ty][c4];
            #pragma unroll
            for (int e = 0; e < 4; ++e)
                #pragma unroll
                for (int bb = 0; bb < 4; ++bb)
                    #pragma unroll
                    for (int vv = 0; vv < 4; ++vv)
                        acc[bb][vv] += hv[bb][e] * wv[vv][e];
        }
    }
    float bias[4];
    #pragma unroll
    for (int vv = 0; vv < 4; ++vv) bias[vv] = fc_b[v0 + 16 * vv + tx];
    #pragma unroll
    for (int bb = 0; bb < 4; ++bb) {
        const int b = 16 * bb + ty;
        #pragma unroll
        for (int vv = 0; vv < 4; ++vv)
            outrow[(size_t)b * OUTROWS + v0 + 16 * vv + tx] = acc[bb][vv] + bias[vv];
    }
}

__global__ __launch_bounds__(1024) void k_softmax(float* __restrict__ outrow,
                                                  int* __restrict__ tok) {
    const int b = blockIdx.x, tid = threadIdx.x;
    float* row = outrow + (size_t)b * OUTROWS;
    __shared__ float sm[1024];
    __shared__ int si[1024];

    float m = -1e30f; int mi = 0;
    for (int v = tid; v < VOCABN; v += 1024) {
        float x = row[v];
        if (x > m) { m = x; mi = v; }
    }
    sm[tid] = m; si[tid] = mi;
    __syncthreads();
    for (int s = 512; s; s >>= 1) {
        if (tid < s) {
            float xo = sm[tid + s]; int io = si[tid + s];
            if (xo > sm[tid] || (xo == sm[tid] && io < si[tid])) { sm[tid] = xo; si[tid] = io; }
        }
        __syncthreads();
    }
    const float M = sm[0];
    const int ami = si[0];
    __syncthreads();

    float sum = 0.f;
    for (int v = tid; v < VOCABN; v += 1024) sum += __expf(row[v] - M);
    sm[tid] = sum;
    __syncthreads();
    for (int s = 512; s; s >>= 1) {
        if (tid < s) sm[tid] += sm[tid + s];
        __syncthreads();
    }
    const float L = M + logf(sm[0]);
    if (tid == 0) tok[b] = ami;

    for (int v = tid; v < VOCABN; v += 1024) row[v] = row[v] - L;
}

extern "C" void kernel_launch(void* const* d_in, const int* in_sizes, int n_in,
                              void* d_out, int out_size, void* d_ws, size_t ws_size,
                              hipStream_t stream) {
    const float* enc_h = (const float*)d_in[0];
    const float* enc_c = (const float*)d_in[1];
    const float* emb   = (const float*)d_in[2];
    const float* W_ih  = (const float*)d_in[3];
    const float* W_hh  = (const float*)d_in[4];
    const float* b_ih  = (const float*)d_in[5];
    const float* b_hh  = (const float*)d_in[6];
    const float* fc_w  = (const float*)d_in[7];
    const float* fc_b  = (const float*)d_in[8];
    float* out = (float*)d_out;

    char* cur = (char*)d_ws;
    float* h    = (float*)cur;            cur += 32768 * 4;
    float* c    = (float*)cur;            cur += 32768 * 4;
    float* part = (float*)cur;            cur += (size_t)GSLICE * 64 * 2048 * 4; // 4 MB
    unsigned short* hhi = (unsigned short*)cur; cur += 32768 * 2;
    unsigned short* hlo = (unsigned short*)cur; cur += 32768 * 2;
    float* pm   = (float*)cur;            cur += (size_t)NVBLK * 64 * 4;
    float* ps   = (float*)cur;            cur += (size_t)NVBLK * 64 * 4;
    int*   pi   = (int*)cur;              cur += (size_t)NVBLK * 64 * 4;
    float* Lb   = (float*)cur;            cur += TSTEPS * 64 * 4;
    int*   tok  = (int*)cur;              cur += 64 * 4;
    int*   counters = (int*)cur;          cur += TSTEPS * 4;
    cur = (char*)(((size_t)cur + 255) & ~(size_t)255);
    unsigned short* whiP = (unsigned short*)cur; cur += (size_t)NVT * 8192 * 2;
    unsigned short* wloP = (unsigned short*)cur; cur += (size_t)NVT * 8192 * 2;
    const size_t NEED = (size_t)(cur - (char*)d_ws);

    if (ws_size >= NEED) {
        k_conv<<<NVT, 256, 0, stream>>>(fc_w, whiP, wloP);
        k_init<<<128, 256, 0, stream>>>(enc_h, enc_c, h, c, tok, counters);
        for (int t = 0; t < TSTEPS; ++t) {
            k_gates<<<32 * GSLICE, 256, 0, stream>>>(W_ih, W_hh, emb, h, tok, part);
            k_cell<<<128, 256, 0, stream>>>(part, b_ih, b_hh, h, c, hhi, hlo);
            float* outrow = out + (size_t)t * VOCABN;
            k_logits<<<NVBLK, 256, 0, stream>>>(whiP, wloP, fc_b, hhi, hlo, outrow,
                                                pm, ps, pi, tok, Lb, counters + t, t);
        }
        k_sub<<<2048, 256, 0, stream>>>(out, Lb);
        k_copyh<<<128, 256, 0, stream>>>(h, out + (size_t)BN * OUTROWS);
    } else {
        // fallback: fp32 logits + fused softmax (round-2 verified structure)
        k_init<<<128, 256, 0, stream>>>(enc_h, enc_c, h, c, tok, counters);
        for (int t = 0; t < TSTEPS; ++t) {
            k_gates<<<32 * GSLICE, 256, 0, stream>>>(W_ih, W_hh, emb, h, tok, part);
            k_cell<<<128, 256, 0, stream>>>(part, b_ih, b_hh, h, c, hhi, hlo);
            float* outrow = out + (size_t)t * VOCABN;
            k_logits_f32<<<500, 256, 0, stream>>>(fc_w, fc_b, h, outrow);
            k_softmax<<<64, 1024, 0, stream>>>(outrow, tok);
        }
        k_copyh<<<128, 256, 0, stream>>>(h, out + (size_t)BN * OUTROWS);
    }
}

// Round 16
// 3419.931 us; speedup vs baseline: 1.4954x; 1.4954x over previous
//
#include <hip/hip_runtime.h>
#include <math.h>

#define VOCABN 32000
#define HIDN 512
#define BN 64
#define TSTEPS 33   // MAX_LEN + 1
#define OUTROWS (TSTEPS * VOCABN)
#define NVBLK 500   // logits grid; each block = 4 waves = 4 16-row v-tiles
#define NVT 2000    // total 16-row v-tiles
#define GSLICE 8    // gates K-slices

typedef float f4 __attribute__((ext_vector_type(4)));
typedef __bf16 bf16x8 __attribute__((ext_vector_type(8)));
typedef unsigned short u16x8 __attribute__((ext_vector_type(8)));

__device__ __forceinline__ unsigned short f2bf_rn(float f) {
    unsigned int u = __builtin_bit_cast(unsigned int, f);
    u += 0x7FFFu + ((u >> 16) & 1u);
    return (unsigned short)(u >> 16);
}
__device__ __forceinline__ float bfbits2f(unsigned short s) {
    unsigned int u = ((unsigned int)s) << 16;
    return __builtin_bit_cast(float, u);
}
__device__ __forceinline__ float sigf(float x) { return 1.f / (1.f + expf(-x)); }
__device__ __forceinline__ void olmerge(float& m, float& s, int& idx,
                                        float mo, float so, int io) {
    float M = fmaxf(m, mo);
    s = s * __expf(m - M) + so * __expf(mo - M);
    idx = (mo > m) ? io : ((mo == m) ? (io < idx ? io : idx) : idx);
    m = M;
}

// ---------------- init ----------------
__global__ __launch_bounds__(256) void k_init(const float* __restrict__ eh,
                                              const float* __restrict__ ec,
                                              float* __restrict__ h,
                                              float* __restrict__ c,
                                              int* __restrict__ tok,
                                              int* __restrict__ counters) {
    int i = blockIdx.x * 256 + threadIdx.x;
    if (i < BN * HIDN) { h[i] = eh[i]; c[i] = ec[i]; }
    if (i < BN) tok[i] = 1; // SOS
    if (i < TSTEPS) counters[i] = 0;
}

// ---------------- one-time: pack fc_w into pre-swizzled bf16 hi/lo A-fragments ----
// layout: whiP[((vt*16 + kc)*64 + lane)*8 + j] = hi(fc_w[vt*16 + (lane&15)][kc*32 + (lane>>4)*8 + j])
__global__ __launch_bounds__(256) void k_conv(const float* __restrict__ fc_w,
                                              unsigned short* __restrict__ whiP,
                                              unsigned short* __restrict__ wloP) {
    const int vt = blockIdx.x;  // 0..1999
    const int tid = threadIdx.x;
    #pragma unroll
    for (int i = 0; i < 4; ++i) {
        const int s = tid + 256 * i;            // 0..1023
        const int kc = s >> 6, lane = s & 63;
        const int v = vt * 16 + (lane & 15);
        const int k = kc * 32 + (lane >> 4) * 8;
        const float* src = fc_w + (size_t)v * 512 + k;
        f4 a = *(const f4*)src;
        f4 b = *(const f4*)(src + 4);
        u16x8 hi, lo;
        #pragma unroll
        for (int e = 0; e < 4; ++e) {
            unsigned short ha = f2bf_rn(a[e]);
            hi[e] = ha; lo[e] = f2bf_rn(a[e] - bfbits2f(ha));
            unsigned short hb = f2bf_rn(b[e]);
            hi[4 + e] = hb; lo[4 + e] = f2bf_rn(b[e] - bfbits2f(hb));
        }
        const size_t o = ((size_t)(vt * 16 + kc) * 64 + lane) * 8;
        *(u16x8*)&whiP[o] = hi;
        *(u16x8*)&wloP[o] = lo;
    }
}

// ---------------- K1a: partial gates GEMM (fp32), 8 K-slices ----------------
// grid = 256 blocks: j0 = (bid&31)*64, ks = bid>>5 (k0 = ks*128)
__global__ __launch_bounds__(256) void k_gates(const float* __restrict__ W_ih,
                                               const float* __restrict__ W_hh,
                                               const float* __restrict__ emb,
                                               const float* __restrict__ h,
                                               const int* __restrict__ tok,
                                               float* __restrict__ part) {
    __shared__ float w_s[64][68];
    __shared__ float x_s[64][68];
    const int tid = threadIdx.x;
    const int j0 = (blockIdx.x & 31) * 64;
    const int ks = blockIdx.x >> 5;          // 0..7
    const int k0 = ks * 128;
    const int tx = tid & 15;
    const int ty = tid >> 4;
    const int r  = tid >> 2;
    const int cq = (tid & 3) * 16;

    float acc[4][4];
    #pragma unroll
    for (int i = 0; i < 4; ++i)
        #pragma unroll
        for (int j = 0; j < 4; ++j) acc[i][j] = 0.f;

    for (int kk = 0; kk < 128; kk += 64) {
        const int k = k0 + kk;               // never straddles the 512 boundary
        __syncthreads();
        {
            const float* src = (k < 512) ? (W_ih + (size_t)(j0 + r) * 512 + k + cq)
                                         : (W_hh + (size_t)(j0 + r) * 512 + (k - 512) + cq);
            const f4* s4 = (const f4*)src;
            f4* d4 = (f4*)&w_s[r][cq];
            d4[0] = s4[0]; d4[1] = s4[1]; d4[2] = s4[2]; d4[3] = s4[3];
        }
        {
            const float* src = (k < 512) ? (emb + (size_t)tok[r] * 512 + k + cq)
                                         : (h + (size_t)r * 512 + (k - 512) + cq);
            const f4* s4 = (const f4*)src;
            f4* d4 = (f4*)&x_s[r][cq];
            d4[0] = s4[0]; d4[1] = s4[1]; d4[2] = s4[2]; d4[3] = s4[3];
        }
        __syncthreads();
        #pragma unroll 4
        for (int c4 = 0; c4 < 64; c4 += 4) {
            f4 wv[4], xv[4];
            #pragma unroll
            for (int jj = 0; jj < 4; ++jj) wv[jj] = *(const f4*)&w_s[16 * jj + tx][c4];
            #pragma unroll
            for (int bb = 0; bb < 4; ++bb) xv[bb] = *(const f4*)&x_s[16 * bb + ty][c4];
            #pragma unroll
            for (int e = 0; e < 4; ++e)
                #pragma unroll
                for (int bb = 0; bb < 4; ++bb)
                    #pragma unroll
                    for (int jj = 0; jj < 4; ++jj)
                        acc[bb][jj] += xv[bb][e] * wv[jj][e];
        }
    }
    #pragma unroll
    for (int bb = 0; bb < 4; ++bb) {
        const int b = 16 * bb + ty;
        #pragma unroll
        for (int jj = 0; jj < 4; ++jj)
            part[((size_t)(ks * 64 + b)) * 2048 + j0 + 16 * jj + tx] = acc[bb][jj];
    }
}

// ---------------- K1b: reduce 8 partials + LSTM cell; writes h + bf16 hi/lo ------
__global__ __launch_bounds__(256) void k_cell(const float* __restrict__ part,
                                              const float* __restrict__ b_ih,
                                              const float* __restrict__ b_hh,
                                              float* __restrict__ h,
                                              float* __restrict__ c,
                                              unsigned short* __restrict__ hhi,
                                              unsigned short* __restrict__ hlo) {
    const int e = blockIdx.x * 256 + threadIdx.x; // b*512+u
    const int b = e >> 9, u = e & 511;
    float g[4];
    #pragma unroll
    for (int gi = 0; gi < 4; ++gi) {
        const int j = gi * 512 + u;
        float s = b_ih[j] + b_hh[j];
        #pragma unroll
        for (int ks = 0; ks < GSLICE; ++ks) s += part[((size_t)(ks * 64 + b)) * 2048 + j];
        g[gi] = s;
    }
    const float ig = sigf(g[0]);
    const float fg = sigf(g[1]);
    const float gg = tanhf(g[2]);
    const float og = sigf(g[3]);
    const float cn = fg * c[e] + ig * gg;
    const float hn = og * tanhf(cn);
    c[e] = cn;
    h[e] = hn;
    const unsigned short hi = f2bf_rn(hn);
    hhi[e] = hi;
    hlo[e] = f2bf_rn(hn - bfbits2f(hi));
}

// ---------------- K2: logits GEMM (round-10 body) + fence-free last-block combine --
// grid 500 x 256. Wave w handles v-tile vt = bid*4+w (16 rows), all 64 b.
// Partials written with relaxed AGENT-scope (sc1) stores -> device-coherent point;
// wave-level s_waitcnt ensures completion before the relaxed AGENT counter bump.
// Last block re-reads partials with AGENT-scope loads and does the wide combine.
__global__ __launch_bounds__(256) void k_logits(const unsigned short* __restrict__ whiP,
                                                const unsigned short* __restrict__ wloP,
                                                const float* __restrict__ fc_b,
                                                const unsigned short* __restrict__ hhi,
                                                const unsigned short* __restrict__ hlo,
                                                float* __restrict__ outrow,
                                                float* __restrict__ pm,
                                                float* __restrict__ ps,
                                                int* __restrict__ pi,
                                                int* __restrict__ tok,
                                                float* __restrict__ Lb,
                                                int* __restrict__ counter,
                                                int t) {
    __shared__ float red_m[4 * 64];
    __shared__ float red_s[4 * 64];
    __shared__ int   red_i[4 * 64];
    __shared__ float cm[256], cs[256];
    __shared__ int   ci[256];
    __shared__ int   isLast;

    const int tid  = threadIdx.x;
    const int w    = tid >> 6;
    const int lane = tid & 63;
    const int li   = lane & 15;
    const int lg   = lane >> 4;
    const int vt   = blockIdx.x * 4 + w;

    f4 acc[4];
    #pragma unroll
    for (int bf = 0; bf < 4; ++bf) acc[bf] = (f4){0.f, 0.f, 0.f, 0.f};

    const unsigned short* Ah = whiP + (size_t)vt * 8192 + lane * 8;
    const unsigned short* Al = wloP + (size_t)vt * 8192 + lane * 8;
    int boff[4];
    #pragma unroll
    for (int bf = 0; bf < 4; ++bf) boff[bf] = (li + 16 * bf) * 512 + lg * 8;

    #pragma unroll 4
    for (int kc = 0; kc < 16; ++kc) {
        bf16x8 Avh = *(const bf16x8*)(Ah + kc * 512);
        bf16x8 Avl = *(const bf16x8*)(Al + kc * 512);
        #pragma unroll
        for (int bf = 0; bf < 4; ++bf) {
            bf16x8 Bh = *(const bf16x8*)&hhi[boff[bf] + kc * 32];
            bf16x8 Bl = *(const bf16x8*)&hlo[boff[bf] + kc * 32];
            acc[bf] = __builtin_amdgcn_mfma_f32_16x16x32_bf16(Avh, Bh, acc[bf], 0, 0, 0);
            acc[bf] = __builtin_amdgcn_mfma_f32_16x16x32_bf16(Avl, Bh, acc[bf], 0, 0, 0);
            acc[bf] = __builtin_amdgcn_mfma_f32_16x16x32_bf16(Avh, Bl, acc[bf], 0, 0, 0);
        }
    }

    // ---- epilogue: bias, store raw logits, per-b online (max, argmax, sumexp) ----
    const int vbase = vt * 16;
    const f4 bias = *(const f4*)&fc_b[vbase + lg * 4];

    #pragma unroll
    for (int bf = 0; bf < 4; ++bf) {
        f4 x = acc[bf] + bias;
        acc[bf] = x;
        const int b = li + 16 * bf;
        *(f4*)&outrow[(size_t)b * OUTROWS + vbase + lg * 4] = x;
    }

    #pragma unroll
    for (int bf = 0; bf < 4; ++bf) {
        float m = -1e30f; int idx = 0;
        #pragma unroll
        for (int rg = 0; rg < 4; ++rg) {
            float x = acc[bf][rg];
            if (x > m) { m = x; idx = vbase + lg * 4 + rg; }
        }
        float s = 0.f;
        #pragma unroll
        for (int rg = 0; rg < 4; ++rg) s += __expf(acc[bf][rg] - m);
        #pragma unroll
        for (int off = 16; off <= 32; off <<= 1) {
            float mo = __shfl_xor(m, off);
            float so = __shfl_xor(s, off);
            int   io = __shfl_xor(idx, off);
            olmerge(m, s, idx, mo, so, io);
        }
        if (lg == 0) {
            red_m[w * 64 + li + 16 * bf] = m;
            red_s[w * 64 + li + 16 * bf] = s;
            red_i[w * 64 + li + 16 * bf] = idx;
        }
    }
    __syncthreads();
    if (tid < 64) {
        float m = red_m[tid]; float s = red_s[tid]; int idx = red_i[tid];
        #pragma unroll
        for (int w2 = 1; w2 < 4; ++w2)
            olmerge(m, s, idx, red_m[w2 * 64 + tid], red_s[w2 * 64 + tid], red_i[w2 * 64 + tid]);
        // relaxed agent-scope (sc1) stores -> device-coherent point, no fence
        __hip_atomic_store(&pm[blockIdx.x * 64 + tid], m, __ATOMIC_RELAXED,
                           __HIP_MEMORY_SCOPE_AGENT);
        __hip_atomic_store(&ps[blockIdx.x * 64 + tid], s, __ATOMIC_RELAXED,
                           __HIP_MEMORY_SCOPE_AGENT);
        __hip_atomic_store(&pi[blockIdx.x * 64 + tid], idx, __ATOMIC_RELAXED,
                           __HIP_MEMORY_SCOPE_AGENT);
    }
    // wave-level drain: partial stores (wave 0) complete at coherent point
    asm volatile("s_waitcnt vmcnt(0)" ::: "memory");
    if (tid == 0) {
        int done = __hip_atomic_fetch_add(counter, 1, __ATOMIC_RELAXED,
                                          __HIP_MEMORY_SCOPE_AGENT);
        isLast = (done == NVBLK - 1) ? 1 : 0;
    }
    __syncthreads();
    if (isLast) {
        const int b = tid & 63;
        const int q = tid >> 6;              // 0..3, each scans 125 blocks
        float m = -1e30f, s = 0.f; int idx = 0;
        #pragma unroll 8
        for (int blk = q * 125; blk < q * 125 + 125; ++blk) {
            float mo = __hip_atomic_load(&pm[blk * 64 + b], __ATOMIC_RELAXED,
                                         __HIP_MEMORY_SCOPE_AGENT);
            float so = __hip_atomic_load(&ps[blk * 64 + b], __ATOMIC_RELAXED,
                                         __HIP_MEMORY_SCOPE_AGENT);
            int   io = __hip_atomic_load(&pi[blk * 64 + b], __ATOMIC_RELAXED,
                                         __HIP_MEMORY_SCOPE_AGENT);
            olmerge(m, s, idx, mo, so, io);
        }
        cm[tid] = m; cs[tid] = s; ci[tid] = idx;
        __syncthreads();
        if (tid < 64) {
            float m0 = cm[tid], s0 = cs[tid]; int i0 = ci[tid];
            #pragma unroll
            for (int q2 = 1; q2 < 4; ++q2)
                olmerge(m0, s0, i0, cm[q2 * 64 + tid], cs[q2 * 64 + tid], ci[q2 * 64 + tid]);
            tok[tid] = i0;
            Lb[t * 64 + tid] = m0 + logf(s0);
        }
    }
}

// ---------------- final: out[b][t][v] -= L[t][b] ----------------
__global__ __launch_bounds__(256) void k_sub(float* __restrict__ out,
                                             const float* __restrict__ Lb) {
    const int N4 = BN * OUTROWS / 4;
    for (int i4 = blockIdx.x * 256 + threadIdx.x; i4 < N4; i4 += gridDim.x * 256) {
        const int i = i4 * 4;
        const int b = i / OUTROWS;
        const int rem = i - b * OUTROWS;
        const int t = rem / VOCABN;
        f4 x = *(const f4*)&out[i];
        const float L = Lb[t * 64 + b];
        x[0] -= L; x[1] -= L; x[2] -= L; x[3] -= L;
        *(f4*)&out[i] = x;
    }
}

// ---------------- final: decoder_hidden = h ----------------
__global__ __launch_bounds__(256) void k_copyh(const float* __restrict__ h,
                                               float* __restrict__ dst) {
    int i = blockIdx.x * 256 + threadIdx.x;
    if (i < BN * HIDN) dst[i] = h[i];
}

// =================== fallback (small ws): fp32 logits + softmax ===========
__global__ __launch_bounds__(256) void k_logits_f32(const float* __restrict__ fc_w,
                                                    const float* __restrict__ fc_b,
                                                    const float* __restrict__ h,
                                                    float* __restrict__ outrow) {
    __shared__ float w_s[64][68];
    __shared__ float h_s[64][68];
    const int tid = threadIdx.x;
    const int v0 = blockIdx.x * 64;
    const int tx = tid & 15;
    const int ty = tid >> 4;
    const int r  = tid >> 2;
    const int cq = (tid & 3) * 16;

    float acc[4][4];
    #pragma unroll
    for (int i = 0; i < 4; ++i)
        #pragma unroll
        for (int j = 0; j < 4; ++j) acc[i][j] = 0.f;

    for (int k = 0; k < 512; k += 64) {
        __syncthreads();
        {
            const f4* s4 = (const f4*)(fc_w + (size_t)(v0 + r) * 512 + k + cq);
            f4* d4 = (f4*)&w_s[r][cq];
            d4[0] = s4[0]; d4[1] = s4[1]; d4[2] = s4[2]; d4[3] = s4[3];
        }
        {
            const f4* s4 = (const f4*)(h + (size_t)r * 512 + k + cq);
            f4* d4 = (f4*)&h_s[r][cq];
            d4[0] = s4[0]; d4[1] = s4[1]; d4[2] = s4[2]; d4[3] = s4[3];
        }
        __syncthreads();
        #pragma unroll 4
        for (int c4 = 0; c4 < 64; c4 += 4) {
            f4 wv[4], hv[4];
            #pragma unroll
            for (int vv = 0; vv < 4; ++vv) wv[vv] = *(const f4*)&w_s[16 * vv + tx][c4];
            #pragma unroll
            for (int bb = 0; bb < 4; ++bb) hv[bb] = *(const f4*)&h_s[16 * bb + ty][c4];
            #pragma unroll
            for (int e = 0; e < 4; ++e)
                #pragma unroll
                for (int bb = 0; bb < 4; ++bb)
                    #pragma unroll
                    for (int vv = 0; vv < 4; ++vv)
                        acc[bb][vv] += hv[bb][e] * wv[vv][e];
        }
    }
    float bias[4];
    #pragma unroll
    for (int vv = 0; vv < 4; ++vv) bias[vv] = fc_b[v0 + 16 * vv + tx];
    #pragma unroll
    for (int bb = 0; bb < 4; ++bb) {
        const int b = 16 * bb + ty;
        #pragma unroll
        for (int vv = 0; vv < 4; ++vv)
            outrow[(size_t)b * OUTROWS + v0 + 16 * vv + tx] = acc[bb][vv] + bias[vv];
    }
}

__global__ __launch_bounds__(1024) void k_softmax(float* __restrict__ outrow,
                                                  int* __restrict__ tok) {
    const int b = blockIdx.x, tid = threadIdx.x;
    float* row = outrow + (size_t)b * OUTROWS;
    __shared__ float sm[1024];
    __shared__ int si[1024];

    float m = -1e30f; int mi = 0;
    for (int v = tid; v < VOCABN; v += 1024) {
        float x = row[v];
        if (x > m) { m = x; mi = v; }
    }
    sm[tid] = m; si[tid] = mi;
    __syncthreads();
    for (int s = 512; s; s >>= 1) {
        if (tid < s) {
            float xo = sm[tid + s]; int io = si[tid + s];
            if (xo > sm[tid] || (xo == sm[tid] && io < si[tid])) { sm[tid] = xo; si[tid] = io; }
        }
        __syncthreads();
    }
    const float M = sm[0];
    const int ami = si[0];
    __syncthreads();

    float sum = 0.f;
    for (int v = tid; v < VOCABN; v += 1024) sum += __expf(row[v] - M);
    sm[tid] = sum;
    __syncthreads();
    for (int s = 512; s; s >>= 1) {
        if (tid < s) sm[tid] += sm[tid + s];
        __syncthreads();
    }
    const float L = M + logf(sm[0]);
    if (tid == 0) tok[b] = ami;

    for (int v = tid; v < VOCABN; v += 1024) row[v] = row[v] - L;
}

extern "C" void kernel_launch(void* const* d_in, const int* in_sizes, int n_in,
                              void* d_out, int out_size, void* d_ws, size_t ws_size,
                              hipStream_t stream) {
    const float* enc_h = (const float*)d_in[0];
    const float* enc_c = (const float*)d_in[1];
    const float* emb   = (const float*)d_in[2];
    const float* W_ih  = (const float*)d_in[3];
    const float* W_hh  = (const float*)d_in[4];
    const float* b_ih  = (const float*)d_in[5];
    const float* b_hh  = (const float*)d_in[6];
    const float* fc_w  = (const float*)d_in[7];
    const float* fc_b  = (const float*)d_in[8];
    float* out = (float*)d_out;

    char* cur = (char*)d_ws;
    float* h    = (float*)cur;            cur += 32768 * 4;
    float* c    = (float*)cur;            cur += 32768 * 4;
    float* part = (float*)cur;            cur += (size_t)GSLICE * 64 * 2048 * 4; // 4 MB
    unsigned short* hhi = (unsigned short*)cur; cur += 32768 * 2;
    unsigned short* hlo = (unsigned short*)cur; cur += 32768 * 2;
    float* pm   = (float*)cur;            cur += (size_t)NVBLK * 64 * 4;
    float* ps   = (float*)cur;            cur += (size_t)NVBLK * 64 * 4;
    int*   pi   = (int*)cur;              cur += (size_t)NVBLK * 64 * 4;
    float* Lb   = (float*)cur;            cur += TSTEPS * 64 * 4;
    int*   tok  = (int*)cur;              cur += 64 * 4;
    int*   counters = (int*)cur;          cur += TSTEPS * 4;
    cur = (char*)(((size_t)cur + 255) & ~(size_t)255);
    unsigned short* whiP = (unsigned short*)cur; cur += (size_t)NVT * 8192 * 2;
    unsigned short* wloP = (unsigned short*)cur; cur += (size_t)NVT * 8192 * 2;
    const size_t NEED = (size_t)(cur - (char*)d_ws);

    if (ws_size >= NEED) {
        k_conv<<<NVT, 256, 0, stream>>>(fc_w, whiP, wloP);
        k_init<<<128, 256, 0, stream>>>(enc_h, enc_c, h, c, tok, counters);
        for (int t = 0; t < TSTEPS; ++t) {
            k_gates<<<32 * GSLICE, 256, 0, stream>>>(W_ih, W_hh, emb, h, tok, part);
            k_cell<<<128, 256, 0, stream>>>(part, b_ih, b_hh, h, c, hhi, hlo);
            float* outrow = out + (size_t)t * VOCABN;
            k_logits<<<NVBLK, 256, 0, stream>>>(whiP, wloP, fc_b, hhi, hlo, outrow,
                                                pm, ps, pi, tok, Lb, counters + t, t);
        }
        k_sub<<<2048, 256, 0, stream>>>(out, Lb);
        k_copyh<<<128, 256, 0, stream>>>(h, out + (size_t)BN * OUTROWS);
    } else {
        // fallback: fp32 logits + fused softmax (round-2 verified structure)
        k_init<<<128, 256, 0, stream>>>(enc_h, enc_c, h, c, tok, counters);
        for (int t = 0; t < TSTEPS; ++t) {
            k_gates<<<32 * GSLICE, 256, 0, stream>>>(W_ih, W_hh, emb, h, tok, part);
            k_cell<<<128, 256, 0, stream>>>(part, b_ih, b_hh, h, c, hhi, hlo);
            float* outrow = out + (size_t)t * VOCABN;
            k_logits_f32<<<500, 256, 0, stream>>>(fc_w, fc_b, h, outrow);
            k_softmax<<<64, 1024, 0, stream>>>(outrow, tok);
        }
        k_copyh<<<128, 256, 0, stream>>>(h, out + (size_t)BN * OUTROWS);
    }
}

// Round 17
// 1941.738 us; speedup vs baseline: 2.6338x; 1.7613x over previous
//
#include <hip/hip_runtime.h>
#include <math.h>

#define VOCABN 32000
#define HIDN 512
#define BN 64
#define TSTEPS 33   // MAX_LEN + 1
#define OUTROWS (TSTEPS * VOCABN)
#define NVBLK 1000  // logits grid; each block = 2 v-tiles x 2 K-halves (4 waves)
#define NVT 2000    // total 16-row v-tiles
#define GSLICE 8    // gates K-slices

typedef float f4 __attribute__((ext_vector_type(4)));
typedef __bf16 bf16x8 __attribute__((ext_vector_type(8)));
typedef unsigned short u16x8 __attribute__((ext_vector_type(8)));

__device__ __forceinline__ unsigned short f2bf_rn(float f) {
    unsigned int u = __builtin_bit_cast(unsigned int, f);
    u += 0x7FFFu + ((u >> 16) & 1u);
    return (unsigned short)(u >> 16);
}
__device__ __forceinline__ float bfbits2f(unsigned short s) {
    unsigned int u = ((unsigned int)s) << 16;
    return __builtin_bit_cast(float, u);
}
__device__ __forceinline__ float sigf(float x) { return 1.f / (1.f + expf(-x)); }
__device__ __forceinline__ void olmerge(float& m, float& s, int& idx,
                                        float mo, float so, int io) {
    float M = fmaxf(m, mo);
    s = s * __expf(m - M) + so * __expf(mo - M);
    idx = (mo > m) ? io : ((mo == m) ? (io < idx ? io : idx) : idx);
    m = M;
}

// ---------------- init ----------------
__global__ __launch_bounds__(256) void k_init(const float* __restrict__ eh,
                                              const float* __restrict__ ec,
                                              float* __restrict__ h,
                                              float* __restrict__ c,
                                              int* __restrict__ tok) {
    int i = blockIdx.x * 256 + threadIdx.x;
    if (i < BN * HIDN) { h[i] = eh[i]; c[i] = ec[i]; }
    if (i < BN) tok[i] = 1; // SOS
}

// ---------------- one-time: pack fc_w into pre-swizzled bf16 hi/lo A-fragments ----
// layout: whiP[((vt*16 + kc)*64 + lane)*8 + j] = hi(fc_w[vt*16 + (lane&15)][kc*32 + (lane>>4)*8 + j])
__global__ __launch_bounds__(256) void k_conv(const float* __restrict__ fc_w,
                                              unsigned short* __restrict__ whiP,
                                              unsigned short* __restrict__ wloP) {
    const int vt = blockIdx.x;  // 0..1999
    const int tid = threadIdx.x;
    #pragma unroll
    for (int i = 0; i < 4; ++i) {
        const int s = tid + 256 * i;            // 0..1023
        const int kc = s >> 6, lane = s & 63;
        const int v = vt * 16 + (lane & 15);
        const int k = kc * 32 + (lane >> 4) * 8;
        const float* src = fc_w + (size_t)v * 512 + k;
        f4 a = *(const f4*)src;
        f4 b = *(const f4*)(src + 4);
        u16x8 hi, lo;
        #pragma unroll
        for (int e = 0; e < 4; ++e) {
            unsigned short ha = f2bf_rn(a[e]);
            hi[e] = ha; lo[e] = f2bf_rn(a[e] - bfbits2f(ha));
            unsigned short hb = f2bf_rn(b[e]);
            hi[4 + e] = hb; lo[4 + e] = f2bf_rn(b[e] - bfbits2f(hb));
        }
        const size_t o = ((size_t)(vt * 16 + kc) * 64 + lane) * 8;
        *(u16x8*)&whiP[o] = hi;
        *(u16x8*)&wloP[o] = lo;
    }
}

// ---------------- K1a: partial gates GEMM (fp32), 8 K-slices ----------------
// grid = 256 blocks: j0 = (bid&31)*64, ks = bid>>5 (k0 = ks*128)
__global__ __launch_bounds__(256) void k_gates(const float* __restrict__ W_ih,
                                               const float* __restrict__ W_hh,
                                               const float* __restrict__ emb,
                                               const float* __restrict__ h,
                                               const int* __restrict__ tok,
                                               float* __restrict__ part) {
    __shared__ float w_s[64][68];
    __shared__ float x_s[64][68];
    const int tid = threadIdx.x;
    const int j0 = (blockIdx.x & 31) * 64;
    const int ks = blockIdx.x >> 5;          // 0..7
    const int k0 = ks * 128;
    const int tx = tid & 15;
    const int ty = tid >> 4;
    const int r  = tid >> 2;
    const int cq = (tid & 3) * 16;

    float acc[4][4];
    #pragma unroll
    for (int i = 0; i < 4; ++i)
        #pragma unroll
        for (int j = 0; j < 4; ++j) acc[i][j] = 0.f;

    for (int kk = 0; kk < 128; kk += 64) {
        const int k = k0 + kk;               // never straddles the 512 boundary
        __syncthreads();
        {
            const float* src = (k < 512) ? (W_ih + (size_t)(j0 + r) * 512 + k + cq)
                                         : (W_hh + (size_t)(j0 + r) * 512 + (k - 512) + cq);
            const f4* s4 = (const f4*)src;
            f4* d4 = (f4*)&w_s[r][cq];
            d4[0] = s4[0]; d4[1] = s4[1]; d4[2] = s4[2]; d4[3] = s4[3];
        }
        {
            const float* src = (k < 512) ? (emb + (size_t)tok[r] * 512 + k + cq)
                                         : (h + (size_t)r * 512 + (k - 512) + cq);
            const f4* s4 = (const f4*)src;
            f4* d4 = (f4*)&x_s[r][cq];
            d4[0] = s4[0]; d4[1] = s4[1]; d4[2] = s4[2]; d4[3] = s4[3];
        }
        __syncthreads();
        #pragma unroll 4
        for (int c4 = 0; c4 < 64; c4 += 4) {
            f4 wv[4], xv[4];
            #pragma unroll
            for (int jj = 0; jj < 4; ++jj) wv[jj] = *(const f4*)&w_s[16 * jj + tx][c4];
            #pragma unroll
            for (int bb = 0; bb < 4; ++bb) xv[bb] = *(const f4*)&x_s[16 * bb + ty][c4];
            #pragma unroll
            for (int e = 0; e < 4; ++e)
                #pragma unroll
                for (int bb = 0; bb < 4; ++bb)
                    #pragma unroll
                    for (int jj = 0; jj < 4; ++jj)
                        acc[bb][jj] += xv[bb][e] * wv[jj][e];
        }
    }
    #pragma unroll
    for (int bb = 0; bb < 4; ++bb) {
        const int b = 16 * bb + ty;
        #pragma unroll
        for (int jj = 0; jj < 4; ++jj)
            part[((size_t)(ks * 64 + b)) * 2048 + j0 + 16 * jj + tx] = acc[bb][jj];
    }
}

// ---------------- K1b: reduce 8 partials + LSTM cell; writes h + bf16 hi/lo ------
__global__ __launch_bounds__(256) void k_cell(const float* __restrict__ part,
                                              const float* __restrict__ b_ih,
                                              const float* __restrict__ b_hh,
                                              float* __restrict__ h,
                                              float* __restrict__ c,
                                              unsigned short* __restrict__ hhi,
                                              unsigned short* __restrict__ hlo) {
    const int e = blockIdx.x * 256 + threadIdx.x; // b*512+u
    const int b = e >> 9, u = e & 511;
    float g[4];
    #pragma unroll
    for (int gi = 0; gi < 4; ++gi) {
        const int j = gi * 512 + u;
        float s = b_ih[j] + b_hh[j];
        #pragma unroll
        for (int ks = 0; ks < GSLICE; ++ks) s += part[((size_t)(ks * 64 + b)) * 2048 + j];
        g[gi] = s;
    }
    const float ig = sigf(g[0]);
    const float fg = sigf(g[1]);
    const float gg = tanhf(g[2]);
    const float og = sigf(g[3]);
    const float cn = fg * c[e] + ig * gg;
    const float hn = og * tanhf(cn);
    c[e] = cn;
    h[e] = hn;
    const unsigned short hi = f2bf_rn(hn);
    hhi[e] = hi;
    hlo[e] = f2bf_rn(hn - bfbits2f(hi));
}

// ---------------- K2: logits GEMM, register path, 2-way K-split ----------------
// grid 1000 x 256 (4 waves). Wave w: vtl = w>>1 (v-tile), kh = w&1 (K-half).
// vt = bid*2 + vtl. Wave computes K-half partial; pairs merge via LDS; wave kh==0
// does the epilogue.
__global__ __launch_bounds__(256, 4) void k_logits(const unsigned short* __restrict__ whiP,
                                                   const unsigned short* __restrict__ wloP,
                                                   const float* __restrict__ fc_b,
                                                   const unsigned short* __restrict__ hhi,
                                                   const unsigned short* __restrict__ hlo,
                                                   float* __restrict__ outrow,
                                                   float* __restrict__ pm,
                                                   float* __restrict__ ps,
                                                   int* __restrict__ pi) {
    __shared__ float sacc[2][16][64];  // [vtl][elem][lane] scalar: conflict-free
    __shared__ float red_m[128];
    __shared__ float red_s[128];
    __shared__ int   red_i[128];

    const int tid  = threadIdx.x;
    const int w    = tid >> 6;
    const int lane = tid & 63;
    const int li   = lane & 15;
    const int lg   = lane >> 4;
    const int vtl  = w >> 1;
    const int kh   = w & 1;
    const int vt   = blockIdx.x * 2 + vtl;

    f4 acc[4];
    #pragma unroll
    for (int bf = 0; bf < 4; ++bf) acc[bf] = (f4){0.f, 0.f, 0.f, 0.f};

    const unsigned short* Ah = whiP + (size_t)vt * 8192 + kh * 4096 + lane * 8;
    const unsigned short* Al = wloP + (size_t)vt * 8192 + kh * 4096 + lane * 8;
    int boff[4];
    #pragma unroll
    for (int bf = 0; bf < 4; ++bf) boff[bf] = (li + 16 * bf) * 512 + kh * 256 + lg * 8;

    #pragma unroll 4
    for (int kc = 0; kc < 8; ++kc) {
        bf16x8 Avh = *(const bf16x8*)(Ah + kc * 512);
        bf16x8 Avl = *(const bf16x8*)(Al + kc * 512);
        #pragma unroll
        for (int bf = 0; bf < 4; ++bf) {
            bf16x8 Bh = *(const bf16x8*)&hhi[boff[bf] + kc * 32];
            bf16x8 Bl = *(const bf16x8*)&hlo[boff[bf] + kc * 32];
            acc[bf] = __builtin_amdgcn_mfma_f32_16x16x32_bf16(Avh, Bh, acc[bf], 0, 0, 0);
            acc[bf] = __builtin_amdgcn_mfma_f32_16x16x32_bf16(Avl, Bh, acc[bf], 0, 0, 0);
            acc[bf] = __builtin_amdgcn_mfma_f32_16x16x32_bf16(Avh, Bl, acc[bf], 0, 0, 0);
        }
    }

    // ---- merge K-half partials: kh==1 writes, kh==0 adds ----
    if (kh == 1) {
        #pragma unroll
        for (int bf = 0; bf < 4; ++bf)
            #pragma unroll
            for (int rg = 0; rg < 4; ++rg)
                sacc[vtl][bf * 4 + rg][lane] = acc[bf][rg];
    }
    __syncthreads();

    if (kh == 0) {
        #pragma unroll
        for (int bf = 0; bf < 4; ++bf)
            #pragma unroll
            for (int rg = 0; rg < 4; ++rg)
                acc[bf][rg] += sacc[vtl][bf * 4 + rg][lane];

        // ---- epilogue: bias, store raw logits, per-b online (max, argmax, sumexp) --
        const int vbase = vt * 16;
        const f4 bias = *(const f4*)&fc_b[vbase + lg * 4];

        #pragma unroll
        for (int bf = 0; bf < 4; ++bf) {
            f4 x = acc[bf] + bias;
            acc[bf] = x;
            const int b = li + 16 * bf;
            *(f4*)&outrow[(size_t)b * OUTROWS + vbase + lg * 4] = x;
        }

        #pragma unroll
        for (int bf = 0; bf < 4; ++bf) {
            float m = -1e30f; int idx = 0;
            #pragma unroll
            for (int rg = 0; rg < 4; ++rg) {
                float x = acc[bf][rg];
                if (x > m) { m = x; idx = vbase + lg * 4 + rg; }
            }
            float s = 0.f;
            #pragma unroll
            for (int rg = 0; rg < 4; ++rg) s += __expf(acc[bf][rg] - m);
            #pragma unroll
            for (int off = 16; off <= 32; off <<= 1) {
                float mo = __shfl_xor(m, off);
                float so = __shfl_xor(s, off);
                int   io = __shfl_xor(idx, off);
                olmerge(m, s, idx, mo, so, io);
            }
            if (lg == 0) {
                red_m[vtl * 64 + li + 16 * bf] = m;
                red_s[vtl * 64 + li + 16 * bf] = s;
                red_i[vtl * 64 + li + 16 * bf] = idx;
            }
        }
    }
    __syncthreads();
    // merge the block's 2 v-tiles per b -> per-block partial
    if (tid < 64) {
        float m = red_m[tid]; float s = red_s[tid]; int idx = red_i[tid];
        olmerge(m, s, idx, red_m[64 + tid], red_s[64 + tid], red_i[64 + tid]);
        pm[blockIdx.x * 64 + tid] = m;
        ps[blockIdx.x * 64 + tid] = s;
        pi[blockIdx.x * 64 + tid] = idx;
    }
}

// ---------------- K3: combine block partials -> tok, L[t][b] (parallel tree) ------
__global__ __launch_bounds__(256) void k_combine(const float* __restrict__ pm,
                                                 const float* __restrict__ ps,
                                                 const int* __restrict__ pi,
                                                 int* __restrict__ tok,
                                                 float* __restrict__ Lb, int t) {
    __shared__ float sm[256], ss[256];
    __shared__ int si[256];
    const int b = blockIdx.x;   // 64 blocks
    const int tid = threadIdx.x;
    float m = -1e30f, s = 0.f; int idx = 0;
    for (int blk = tid; blk < NVBLK; blk += 256)
        olmerge(m, s, idx, pm[blk * 64 + b], ps[blk * 64 + b], pi[blk * 64 + b]);
    sm[tid] = m; ss[tid] = s; si[tid] = idx;
    __syncthreads();
    for (int st = 128; st; st >>= 1) {
        if (tid < st) {
            float m0 = sm[tid], s0 = ss[tid]; int i0 = si[tid];
            olmerge(m0, s0, i0, sm[tid + st], ss[tid + st], si[tid + st]);
            sm[tid] = m0; ss[tid] = s0; si[tid] = i0;
        }
        __syncthreads();
    }
    if (tid == 0) { tok[b] = si[0]; Lb[t * 64 + b] = sm[0] + logf(ss[0]); }
}

// ---------------- final: out[b][t][v] -= L[t][b] ----------------
__global__ __launch_bounds__(256) void k_sub(float* __restrict__ out,
                                             const float* __restrict__ Lb) {
    const int N4 = BN * OUTROWS / 4;
    for (int i4 = blockIdx.x * 256 + threadIdx.x; i4 < N4; i4 += gridDim.x * 256) {
        const int i = i4 * 4;
        const int b = i / OUTROWS;
        const int rem = i - b * OUTROWS;
        const int t = rem / VOCABN;
        f4 x = *(const f4*)&out[i];
        const float L = Lb[t * 64 + b];
        x[0] -= L; x[1] -= L; x[2] -= L; x[3] -= L;
        *(f4*)&out[i] = x;
    }
}

// ---------------- final: decoder_hidden = h ----------------
__global__ __launch_bounds__(256) void k_copyh(const float* __restrict__ h,
                                               float* __restrict__ dst) {
    int i = blockIdx.x * 256 + threadIdx.x;
    if (i < BN * HIDN) dst[i] = h[i];
}

// =================== fallback (small ws): fp32 logits + softmax ===========
__global__ __launch_bounds__(256) void k_logits_f32(const float* __restrict__ fc_w,
                                                    const float* __restrict__ fc_b,
                                                    const float* __restrict__ h,
                                                    float* __restrict__ outrow) {
    __shared__ float w_s[64][68];
    __shared__ float h_s[64][68];
    const int tid = threadIdx.x;
    const int v0 = blockIdx.x * 64;
    const int tx = tid & 15;
    const int ty = tid >> 4;
    const int r  = tid >> 2;
    const int cq = (tid & 3) * 16;

    float acc[4][4];
    #pragma unroll
    for (int i = 0; i < 4; ++i)
        #pragma unroll
        for (int j = 0; j < 4; ++j) acc[i][j] = 0.f;

    for (int k = 0; k < 512; k += 64) {
        __syncthreads();
        {
            const f4* s4 = (const f4*)(fc_w + (size_t)(v0 + r) * 512 + k + cq);
            f4* d4 = (f4*)&w_s[r][cq];
            d4[0] = s4[0]; d4[1] = s4[1]; d4[2] = s4[2]; d4[3] = s4[3];
        }
        {
            const f4* s4 = (const f4*)(h + (size_t)r * 512 + k + cq);
            f4* d4 = (f4*)&h_s[r][cq];
            d4[0] = s4[0]; d4[1] = s4[1]; d4[2] = s4[2]; d4[3] = s4[3];
        }
        __syncthreads();
        #pragma unroll 4
        for (int c4 = 0; c4 < 64; c4 += 4) {
            f4 wv[4], hv[4];
            #pragma unroll
            for (int vv = 0; vv < 4; ++vv) wv[vv] = *(const f4*)&w_s[16 * vv + tx][c4];
            #pragma unroll
            for (int bb = 0; bb < 4; ++bb) hv[bb] = *(const f4*)&h_s[16 * bb + ty][c4];
            #pragma unroll
            for (int e = 0; e < 4; ++e)
                #pragma unroll
                for (int bb = 0; bb < 4; ++bb)
                    #pragma unroll
                    for (int vv = 0; vv < 4; ++vv)
                        acc[bb][vv] += hv[bb][e] * wv[vv][e];
        }
    }
    float bias[4];
    #pragma unroll
    for (int vv = 0; vv < 4; ++vv) bias[vv] = fc_b[v0 + 16 * vv + tx];
    #pragma unroll
    for (int bb = 0; bb < 4; ++bb) {
        const int b = 16 * bb + ty;
        #pragma unroll
        for (int vv = 0; vv < 4; ++vv)
            outrow[(size_t)b * OUTROWS + v0 + 16 * vv + tx] = acc[bb][vv] + bias[vv];
    }
}

__global__ __launch_bounds__(1024) void k_softmax(float* __restrict__ outrow,
                                                  int* __restrict__ tok) {
    const int b = blockIdx.x, tid = threadIdx.x;
    float* row = outrow + (size_t)b * OUTROWS;
    __shared__ float sm[1024];
    __shared__ int si[1024];

    float m = -1e30f; int mi = 0;
    for (int v = tid; v < VOCABN; v += 1024) {
        float x = row[v];
        if (x > m) { m = x; mi = v; }
    }
    sm[tid] = m; si[tid] = mi;
    __syncthreads();
    for (int s = 512; s; s >>= 1) {
        if (tid < s) {
            float xo = sm[tid + s]; int io = si[tid + s];
            if (xo > sm[tid] || (xo == sm[tid] && io < si[tid])) { sm[tid] = xo; si[tid] = io; }
        }
        __syncthreads();
    }
    const float M = sm[0];
    const int ami = si[0];
    __syncthreads();

    float sum = 0.f;
    for (int v = tid; v < VOCABN; v += 1024) sum += __expf(row[v] - M);
    sm[tid] = sum;
    __syncthreads();
    for (int s = 512; s; s >>= 1) {
        if (tid < s) sm[tid] += sm[tid + s];
        __syncthreads();
    }
    const float L = M + logf(sm[0]);
    if (tid == 0) tok[b] = ami;

    for (int v = tid; v < VOCABN; v += 1024) row[v] = row[v] - L;
}

extern "C" void kernel_launch(void* const* d_in, const int* in_sizes, int n_in,
                              void* d_out, int out_size, void* d_ws, size_t ws_size,
                              hipStream_t stream) {
    const float* enc_h = (const float*)d_in[0];
    const float* enc_c = (const float*)d_in[1];
    const float* emb   = (const float*)d_in[2];
    const float* W_ih  = (const float*)d_in[3];
    const float* W_hh  = (const float*)d_in[4];
    const float* b_ih  = (const float*)d_in[5];
    const float* b_hh  = (const float*)d_in[6];
    const float* fc_w  = (const float*)d_in[7];
    const float* fc_b  = (const float*)d_in[8];
    float* out = (float*)d_out;

    char* cur = (char*)d_ws;
    float* h    = (float*)cur;            cur += 32768 * 4;
    float* c    = (float*)cur;            cur += 32768 * 4;
    float* part = (float*)cur;            cur += (size_t)GSLICE * 64 * 2048 * 4; // 4 MB
    unsigned short* hhi = (unsigned short*)cur; cur += 32768 * 2;
    unsigned short* hlo = (unsigned short*)cur; cur += 32768 * 2;
    float* pm   = (float*)cur;            cur += (size_t)NVBLK * 64 * 4;
    float* ps   = (float*)cur;            cur += (size_t)NVBLK * 64 * 4;
    int*   pi   = (int*)cur;              cur += (size_t)NVBLK * 64 * 4;
    float* Lb   = (float*)cur;            cur += TSTEPS * 64 * 4;
    int*   tok  = (int*)cur;              cur += 64 * 4;
    unsigned short* whiP = (unsigned short*)cur; cur += (size_t)NVT * 8192 * 2;
    unsigned short* wloP = (unsigned short*)cur; cur += (size_t)NVT * 8192 * 2;
    const size_t NEED = (size_t)(cur - (char*)d_ws);

    if (ws_size >= NEED) {
        k_conv<<<NVT, 256, 0, stream>>>(fc_w, whiP, wloP);
        k_init<<<128, 256, 0, stream>>>(enc_h, enc_c, h, c, tok);
        for (int t = 0; t < TSTEPS; ++t) {
            k_gates<<<32 * GSLICE, 256, 0, stream>>>(W_ih, W_hh, emb, h, tok, part);
            k_cell<<<128, 256, 0, stream>>>(part, b_ih, b_hh, h, c, hhi, hlo);
            float* outrow = out + (size_t)t * VOCABN;
            k_logits<<<NVBLK, 256, 0, stream>>>(whiP, wloP, fc_b, hhi, hlo, outrow, pm, ps, pi);
            k_combine<<<64, 256, 0, stream>>>(pm, ps, pi, tok, Lb, t);
        }
        k_sub<<<2048, 256, 0, stream>>>(out, Lb);
        k_copyh<<<128, 256, 0, stream>>>(h, out + (size_t)BN * OUTROWS);
    } else {
        // fallback: fp32 logits + fused softmax (round-2 verified structure)
        k_init<<<128, 256, 0, stream>>>(enc_h, enc_c, h, c, tok);
        for (int t = 0; t < TSTEPS; ++t) {
            k_gates<<<32 * GSLICE, 256, 0, stream>>>(W_ih, W_hh, emb, h, tok, part);
            k_cell<<<128, 256, 0, stream>>>(part, b_ih, b_hh, h, c, hhi, hlo);
            float* outrow = out + (size_t)t * VOCABN;
            k_logits_f32<<<500, 256, 0, stream>>>(fc_w, fc_b, h, outrow);
            k_softmax<<<64, 1024, 0, stream>>>(outrow, tok);
        }
        k_copyh<<<128, 256, 0, stream>>>(h, out + (size_t)BN * OUTROWS);
    }
}